// Round 1
// baseline (442.738 us; speedup 1.0000x reference)
//
#include <hip/hip_runtime.h>
#include <math.h>

// ROI-Align over FPN levels p2..p5 (NHWC, C=256), 7x7 pool, output permuted
// by stable argsort of roi_level.
//
// Kernel 1 (setup): per-ROI level + stable scatter position (matches
// jnp.argsort stable semantics: sort by level, ties by original index).
// Kernel 2 (main): one 64-lane wave per (roi, bin); each lane does 4 channels
// as float4. Fully coalesced reads/writes.

#define MAX_R 2048   // R = B*N = 2000 in this problem

__global__ void roi_setup_kernel(const float* __restrict__ rois,
                                 const int* __restrict__ image_h,
                                 const int* __restrict__ image_w,
                                 int R,
                                 int* __restrict__ level_out,
                                 int* __restrict__ pos_out) {
    __shared__ int lvl[MAX_R];
    const int t = threadIdx.x;
    // canonical scale: 224 / sqrt(image_area), exact for 1024x1024 (0.21875)
    const float canon = 224.0f / sqrtf((float)(image_h[0] * image_w[0]));
    for (int r = t; r < R; r += blockDim.x) {
        const float y1 = rois[r * 4 + 0];
        const float x1 = rois[r * 4 + 1];
        const float y2 = rois[r * 4 + 2];
        const float x2 = rois[r * 4 + 3];
        const float h = y2 - y1;
        const float w = x2 - x1;
        const float hw = h * w;
        const float s = sqrtf(fmaxf(hw, 1e-12f));
        // double log2 + rint: round-half-to-even, matching jnp.round
        const double spec = log2((double)s / (double)canon);
        int l = 4 + (int)rint(spec);
        l = min(5, max(2, l));
        lvl[r] = l - 2;   // 0..3
    }
    __syncthreads();
    if (t == 0) {
        // stable positions: base offset per level + rank within level in
        // original index order (== stable argsort of level)
        int cnt[4] = {0, 0, 0, 0};
        for (int r = 0; r < R; ++r) cnt[lvl[r]]++;
        int base[4];
        int acc = 0;
        for (int i = 0; i < 4; ++i) { base[i] = acc; acc += cnt[i]; }
        int run[4] = {0, 0, 0, 0};
        for (int r = 0; r < R; ++r) {
            const int l = lvl[r];
            pos_out[r] = base[l] + run[l]++;
            level_out[r] = l;
        }
    }
}

__global__ __launch_bounds__(64)
void roi_align_kernel(const float* __restrict__ rois,
                      const float* __restrict__ p2,
                      const float* __restrict__ p3,
                      const float* __restrict__ p4,
                      const float* __restrict__ p5,
                      const int* __restrict__ level,
                      const int* __restrict__ pos,
                      float* __restrict__ out,
                      int N) {
    const int gb  = blockIdx.x;
    const int r   = gb / 49;
    const int bin = gb % 49;
    const int py  = bin / 7;
    const int px  = bin % 7;
    const int b   = r / N;

    const int l = level[r];
    const float* feat;
    int H;
    switch (l) {
        case 0:  feat = p2; H = 256; break;
        case 1:  feat = p3; H = 128; break;
        case 2:  feat = p4; H = 64;  break;
        default: feat = p5; H = 32;  break;
    }
    const int W = H;

    const float y1 = rois[r * 4 + 0];
    const float x1 = rois[r * 4 + 1];
    const float y2 = rois[r * 4 + 2];
    const float x2 = rois[r * 4 + 3];
    const float h = y2 - y1;
    const float w = x2 - x1;

    // match reference op order: (y1 + fy*(y2-y1)) * (H-1), fy = py/6
    const float fy = (float)py / 6.0f;
    const float fx = (float)px / 6.0f;
    const float in_y = (y1 + fy * h) * (float)(H - 1);
    const float in_x = (x1 + fx * w) * (float)(W - 1);

    const float y0f = floorf(in_y);
    const float x0f = floorf(in_x);
    const float wy = in_y - y0f;
    const float wx = in_x - x0f;
    const int y0i = (int)y0f;
    const int x0i = (int)x0f;
    const int y0c = min(H - 1, max(0, y0i));
    const int y1c = min(H - 1, max(0, y0i + 1));
    const int x0c = min(W - 1, max(0, x0i));
    const int x1c = min(W - 1, max(0, x0i + 1));

    const float vmask = (in_y >= 0.0f && in_y <= (float)(H - 1) &&
                         in_x >= 0.0f && in_x <= (float)(W - 1)) ? 1.0f : 0.0f;

    // float4 indexing: 64 float4 per pixel (256 channels)
    const float4* __restrict__ f4 = (const float4*)feat;
    const int c = threadIdx.x;            // 0..63
    const size_t bb = (size_t)b * H * W * 64;
    const size_t i00 = bb + ((size_t)y0c * W + x0c) * 64 + c;
    const size_t i01 = bb + ((size_t)y0c * W + x1c) * 64 + c;
    const size_t i10 = bb + ((size_t)y1c * W + x0c) * 64 + c;
    const size_t i11 = bb + ((size_t)y1c * W + x1c) * 64 + c;

    const float4 v00 = f4[i00];
    const float4 v01 = f4[i01];
    const float4 v10 = f4[i10];
    const float4 v11 = f4[i11];

    const float omwx = 1.0f - wx;
    const float omwy = 1.0f - wy;

    float4 res;
    {
        const float tx = v00.x * omwx + v01.x * wx;
        const float bx = v10.x * omwx + v11.x * wx;
        res.x = (tx * omwy + bx * wy) * vmask;
        const float ty = v00.y * omwx + v01.y * wx;
        const float by = v10.y * omwx + v11.y * wx;
        res.y = (ty * omwy + by * wy) * vmask;
        const float tz = v00.z * omwx + v01.z * wx;
        const float bz = v10.z * omwx + v11.z * wx;
        res.z = (tz * omwy + bz * wy) * vmask;
        const float tw = v00.w * omwx + v01.w * wx;
        const float bw = v10.w * omwx + v11.w * wx;
        res.w = (tw * omwy + bw * wy) * vmask;
    }

    float4* __restrict__ o4 = (float4*)out;
    const size_t o = ((size_t)pos[r] * 49 + bin) * 64 + c;
    o4[o] = res;
}

extern "C" void kernel_launch(void* const* d_in, const int* in_sizes, int n_in,
                              void* d_out, int out_size, void* d_ws, size_t ws_size,
                              hipStream_t stream) {
    const float* rois = (const float*)d_in[0];
    const int*   ih   = (const int*)d_in[1];
    const int*   iw   = (const int*)d_in[2];
    const float* p2   = (const float*)d_in[3];
    const float* p3   = (const float*)d_in[4];
    const float* p4   = (const float*)d_in[5];
    const float* p5   = (const float*)d_in[6];

    const int R = in_sizes[0] / 4;                       // B*N
    const int B = in_sizes[3] / (256 * 256 * 256);       // p2 is (B,256,256,256)
    const int N = R / B;

    int* level = (int*)d_ws;
    int* pos   = level + R;

    roi_setup_kernel<<<1, 1024, 0, stream>>>(rois, ih, iw, R, level, pos);
    roi_align_kernel<<<R * 49, 64, 0, stream>>>(rois, p2, p3, p4, p5,
                                                level, pos, (float*)d_out, N);
}

// Round 2
// 264.488 us; speedup vs baseline: 1.6739x; 1.6739x over previous
//
#include <hip/hip_runtime.h>
#include <math.h>

// ROI-Align over FPN levels p2..p5 (NHWC, C=256), 7x7 pool, output permuted
// by stable argsort of roi_level.
//
// Kernel 1 (setup): per-ROI level + stable scatter position. Parallel:
// ballot-based within-chunk rank (64-wide chunks) + tiny serial chunk scan.
// Kernel 2 (main): grid-stride persistent waves, 2 bins per wave-iteration
// (8 outstanding 1 KB loads) for memory-level parallelism.

#define MAX_R 2048   // R = B*N = 2000 in this problem
#define NCHUNK_MAX (MAX_R / 64)

__global__ __launch_bounds__(1024)
void roi_setup_kernel(const float* __restrict__ rois,
                      const int* __restrict__ image_h,
                      const int* __restrict__ image_w,
                      int R,
                      int* __restrict__ level_out,
                      int* __restrict__ pos_out) {
    __shared__ int lvl_sh[MAX_R];
    __shared__ int wrank_sh[MAX_R];
    __shared__ int chunk_cnt[NCHUNK_MAX][4];
    __shared__ int chunk_base[NCHUNK_MAX][4];

    const int t    = threadIdx.x;
    const int lane = t & 63;
    const int wave = t >> 6;
    const int nwaves = blockDim.x >> 6;
    const int nchunk = (R + 63) / 64;

    const float canon = 224.0f / sqrtf((float)(image_h[0] * image_w[0]));

    // Phase 1+2: level + within-chunk stable rank via ballot
    for (int c = wave; c < nchunk; c += nwaves) {
        const int r = c * 64 + lane;
        int l = -1;
        if (r < R) {
            const float y1 = rois[r * 4 + 0];
            const float x1 = rois[r * 4 + 1];
            const float y2 = rois[r * 4 + 2];
            const float x2 = rois[r * 4 + 3];
            const float hw = (y2 - y1) * (x2 - x1);
            const float s = sqrtf(fmaxf(hw, 1e-12f));
            // double log2 + rint: round-half-to-even, matching jnp.round
            const double spec = log2((double)s / (double)canon);
            l = 4 + (int)rint(spec);
            l = min(5, max(2, l)) - 2;   // 0..3
            lvl_sh[r] = l;
        }
        unsigned long long m[4];
        #pragma unroll
        for (int i = 0; i < 4; ++i) m[i] = __ballot(l == i);
        if (r < R) {
            const unsigned long long below = (1ull << lane) - 1ull;
            wrank_sh[r] = __popcll(m[l] & below);
        }
        if (lane < 4) chunk_cnt[c][lane] = __popcll(m[lane]);
    }
    __syncthreads();

    // Phase 3: tiny serial scan (nchunk<=32, 4 levels)
    if (t == 0) {
        int tot[4] = {0, 0, 0, 0};
        for (int c = 0; c < nchunk; ++c)
            for (int l = 0; l < 4; ++l) {
                chunk_base[c][l] = tot[l];
                tot[l] += chunk_cnt[c][l];
            }
        int base[4];
        int acc = 0;
        for (int l = 0; l < 4; ++l) { base[l] = acc; acc += tot[l]; }
        for (int c = 0; c < nchunk; ++c)
            for (int l = 0; l < 4; ++l) chunk_base[c][l] += base[l];
    }
    __syncthreads();

    // Phase 4: scatter positions
    for (int r = t; r < R; r += blockDim.x) {
        const int l = lvl_sh[r];
        level_out[r] = l;
        pos_out[r] = chunk_base[r >> 6][l] + wrank_sh[r];
    }
}

struct BinTask {
    const float4* f4;
    size_t i00, i01, i10, i11, oidx;
    float wx, wy, vmask;
};

__device__ __forceinline__ BinTask make_task(int work, int N,
        const float* __restrict__ rois,
        const int* __restrict__ level,
        const int* __restrict__ pos,
        const float* __restrict__ p2, const float* __restrict__ p3,
        const float* __restrict__ p4, const float* __restrict__ p5,
        int lane) {
    BinTask T;
    const int r   = work / 49;
    const int bin = work % 49;
    const int py  = bin / 7;
    const int px  = bin % 7;
    const int b   = r / N;

    const int l = level[r];
    const float* feat;
    int H;
    switch (l) {
        case 0:  feat = p2; H = 256; break;
        case 1:  feat = p3; H = 128; break;
        case 2:  feat = p4; H = 64;  break;
        default: feat = p5; H = 32;  break;
    }
    const int W = H;

    const float y1 = rois[r * 4 + 0];
    const float x1 = rois[r * 4 + 1];
    const float y2 = rois[r * 4 + 2];
    const float x2 = rois[r * 4 + 3];

    // match reference op order: (y1 + fy*(y2-y1)) * (H-1), fy = py/6
    const float fy = (float)py / 6.0f;
    const float fx = (float)px / 6.0f;
    const float in_y = (y1 + fy * (y2 - y1)) * (float)(H - 1);
    const float in_x = (x1 + fx * (x2 - x1)) * (float)(W - 1);

    const float y0f = floorf(in_y);
    const float x0f = floorf(in_x);
    T.wy = in_y - y0f;
    T.wx = in_x - x0f;
    const int y0i = (int)y0f;
    const int x0i = (int)x0f;
    const int y0c = min(H - 1, max(0, y0i));
    const int y1c = min(H - 1, max(0, y0i + 1));
    const int x0c = min(W - 1, max(0, x0i));
    const int x1c = min(W - 1, max(0, x0i + 1));

    T.vmask = (in_y >= 0.0f && in_y <= (float)(H - 1) &&
               in_x >= 0.0f && in_x <= (float)(W - 1)) ? 1.0f : 0.0f;

    T.f4 = (const float4*)feat;
    const size_t bb = (size_t)b * H * W * 64;
    T.i00 = bb + ((size_t)y0c * W + x0c) * 64 + lane;
    T.i01 = bb + ((size_t)y0c * W + x1c) * 64 + lane;
    T.i10 = bb + ((size_t)y1c * W + x0c) * 64 + lane;
    T.i11 = bb + ((size_t)y1c * W + x1c) * 64 + lane;
    T.oidx = ((size_t)pos[r] * 49 + bin) * 64 + lane;
    return T;
}

__device__ __forceinline__ float4 blend(float4 v00, float4 v01,
                                        float4 v10, float4 v11,
                                        float wx, float wy, float vmask) {
    const float omwx = 1.0f - wx;
    const float omwy = 1.0f - wy;
    float4 res;
    res.x = ((v00.x * omwx + v01.x * wx) * omwy + (v10.x * omwx + v11.x * wx) * wy) * vmask;
    res.y = ((v00.y * omwx + v01.y * wx) * omwy + (v10.y * omwx + v11.y * wx) * wy) * vmask;
    res.z = ((v00.z * omwx + v01.z * wx) * omwy + (v10.z * omwx + v11.z * wx) * wy) * vmask;
    res.w = ((v00.w * omwx + v01.w * wx) * omwy + (v10.w * omwx + v11.w * wx) * wy) * vmask;
    return res;
}

__global__ __launch_bounds__(256)
void roi_align_kernel(const float* __restrict__ rois,
                      const float* __restrict__ p2,
                      const float* __restrict__ p3,
                      const float* __restrict__ p4,
                      const float* __restrict__ p5,
                      const int* __restrict__ level,
                      const int* __restrict__ pos,
                      float* __restrict__ out,
                      int N, int total) {
    const int lane   = threadIdx.x & 63;
    const int wave   = blockIdx.x * (blockDim.x >> 6) + (threadIdx.x >> 6);
    const int nwaves = gridDim.x * (blockDim.x >> 6);
    float4* __restrict__ o4 = (float4*)out;

    for (int w0 = wave * 2; w0 < total; w0 += nwaves * 2) {
        const bool hasB = (w0 + 1) < total;
        BinTask A = make_task(w0, N, rois, level, pos, p2, p3, p4, p5, lane);
        BinTask B = make_task(hasB ? w0 + 1 : w0, N, rois, level, pos, p2, p3, p4, p5, lane);

        // issue all 8 loads before any use
        const float4 a00 = A.f4[A.i00];
        const float4 a01 = A.f4[A.i01];
        const float4 a10 = A.f4[A.i10];
        const float4 a11 = A.f4[A.i11];
        const float4 b00 = B.f4[B.i00];
        const float4 b01 = B.f4[B.i01];
        const float4 b10 = B.f4[B.i10];
        const float4 b11 = B.f4[B.i11];

        o4[A.oidx] = blend(a00, a01, a10, a11, A.wx, A.wy, A.vmask);
        if (hasB)
            o4[B.oidx] = blend(b00, b01, b10, b11, B.wx, B.wy, B.vmask);
    }
}

extern "C" void kernel_launch(void* const* d_in, const int* in_sizes, int n_in,
                              void* d_out, int out_size, void* d_ws, size_t ws_size,
                              hipStream_t stream) {
    const float* rois = (const float*)d_in[0];
    const int*   ih   = (const int*)d_in[1];
    const int*   iw   = (const int*)d_in[2];
    const float* p2   = (const float*)d_in[3];
    const float* p3   = (const float*)d_in[4];
    const float* p4   = (const float*)d_in[5];
    const float* p5   = (const float*)d_in[6];

    const int R = in_sizes[0] / 4;                       // B*N
    const int B = in_sizes[3] / (256 * 256 * 256);       // p2 is (B,256,256,256)
    const int N = R / B;
    const int total = R * 49;

    int* level = (int*)d_ws;
    int* pos   = level + R;

    roi_setup_kernel<<<1, 1024, 0, stream>>>(rois, ih, iw, R, level, pos);
    // 2048 blocks x 4 waves = 8192 waves; 2 bins/wave-iter -> ~6 iters/wave
    roi_align_kernel<<<2048, 256, 0, stream>>>(rois, p2, p3, p4, p5,
                                               level, pos, (float*)d_out, N, total);
}